// Round 7
// baseline (156.475 us; speedup 1.0000x reference)
//
#include <hip/hip_runtime.h>
#include <hip/hip_bf16.h>

#define NB 4
#define C 128
#define N 4096          // 64*64
#define EPS 1e-6f
#define PW 80           // padded image width (x in [-8, 71])
#define PIMG 5120       // 64*80 padded pixels per image

typedef float f32x4 __attribute__((ext_vector_type(4)));
typedef short bf16x8 __attribute__((ext_vector_type(8)));
typedef unsigned short ushort_t;
typedef unsigned int uint_t;

__device__ __forceinline__ ushort_t f2bf(float f) {
  __hip_bfloat16 h = __float2bfloat16(f);
  return *reinterpret_cast<ushort_t*>(&h);
}

struct alignas(8) us4 { ushort_t a, b, c, d; };

// ====== prep_misc: frag-order bf16 weights + both 32x32 convs + dsum zero ======
// conv threads own 2 px (float2) x 4 o-ch = 8 indep FMA chains per c-iter;
// weight reads are block-uniform (SGPR). FMA order per element bit-identical.
__device__ __forceinline__ void conv_body(const float* __restrict__ x,
                                          const float* __restrict__ w,
                                          const float* __restrict__ bias,
                                          float* __restrict__ out,
                                          int n0, int o0, int b, int CIN) {
  const float* xb = x + (size_t)(b * CIN) * 1024 + n0;
  float ax0 = 0.f, ay0 = 0.f, ax1 = 0.f, ay1 = 0.f;
  float ax2 = 0.f, ay2 = 0.f, ax3 = 0.f, ay3 = 0.f;
#pragma unroll 4
  for (int c = 0; c < CIN; ++c) {
    float2 xv = *(const float2*)(xb + (size_t)c * 1024);
    float w0 = w[(o0 + 0) * CIN + c];
    float w1 = w[(o0 + 1) * CIN + c];
    float w2 = w[(o0 + 2) * CIN + c];
    float w3 = w[(o0 + 3) * CIN + c];
    ax0 += w0 * xv.x; ay0 += w0 * xv.y;
    ax1 += w1 * xv.x; ay1 += w1 * xv.y;
    ax2 += w2 * xv.x; ay2 += w2 * xv.y;
    ax3 += w3 * xv.x; ay3 += w3 * xv.y;
  }
  size_t ob = ((size_t)b * 128 + o0) * 1024 + n0;
  float b0 = bias[o0], b1 = bias[o0 + 1], b2 = bias[o0 + 2], b3 = bias[o0 + 3];
  *(float2*)(out + ob)        = make_float2(ax0 + b0, ay0 + b0);
  *(float2*)(out + ob + 1024) = make_float2(ax1 + b1, ay1 + b1);
  *(float2*)(out + ob + 2048) = make_float2(ax2 + b2, ay2 + b2);
  *(float2*)(out + ob + 3072) = make_float2(ax3 + b3, ay3 + b3);
}

__global__ void prep_misc(const float* __restrict__ edge_f, const float* __restrict__ w_align,
                          const float* __restrict__ b_align,
                          const float* __restrict__ fused_f, const float* __restrict__ w_fal,
                          const float* __restrict__ b_fal,
                          const float* __restrict__ wq, const float* __restrict__ wk,
                          const float* __restrict__ wf,
                          ushort_t* __restrict__ wqf, ushort_t* __restrict__ wkf,
                          ushort_t* __restrict__ wff,
                          float* __restrict__ edge32, float* __restrict__ fused32,
                          float* __restrict__ dsum) {
  int bx = blockIdx.x, t = threadIdx.x;
  if (bx < 64) {
    if (bx == 0 && t < NB) dsum[t] = 0.f;
    int c = bx * 256 + t;                  // chunk id 0..16383
    int lane = c & 63;
    int mrow = lane & 15, quad = lane >> 4;
    if (c < 4096) {                        // wqf: 16 tiles x 4 kslots (K=128, concat folded)
      int grp = c >> 6;
      int tile = grp >> 2, kslot = grp & 3;
      int o = tile * 16 + mrow, k0 = kslot * 32 + quad * 8;
      const float* s = wq + o * 256 + k0;
      ushort_t* d = wqf + (size_t)c * 8;
#pragma unroll
      for (int j = 0; j < 8; ++j) d[j] = f2bf(s[j] + s[128 + j]);
    } else if (c < 12288) {                // wkf: 16 tiles x 8 kslots (K=256)
      int c2 = c - 4096;
      int grp = c2 >> 6;
      int tile = grp >> 3, kslot = grp & 7;
      int o = tile * 16 + mrow, k0 = kslot * 32 + quad * 8;
      const float* s = wk + o * 256 + k0;
      ushort_t* d = wkf + (size_t)c2 * 8;
#pragma unroll
      for (int j = 0; j < 8; ++j) d[j] = f2bf(s[j]);
    } else {                               // wff: 8 tiles x 8 kslots (K=256)
      int c2 = c - 12288;
      int grp = c2 >> 6;
      int tile = grp >> 3, kslot = grp & 7;
      int o = tile * 16 + mrow, k0 = kslot * 32 + quad * 8;
      const float* s = wf + o * 256 + k0;
      ushort_t* d = wff + (size_t)c2 * 8;
#pragma unroll
      for (int j = 0; j < 8; ++j) d[j] = f2bf(s[j]);
    }
  } else if (bx < 320) {
    int j = bx - 64;                       // edge conv: 256 blocks
    int b = j >> 6, rem = j & 63;
    int og = rem >> 1, half = rem & 1;
    conv_body(edge_f, w_align, b_align, edge32, half * 512 + t * 2, og * 4, b, 64);
  } else {
    int j = bx - 320;                      // fused conv: 256 blocks
    int b = j >> 6, rem = j & 63;
    int og = rem >> 1, half = rem & 1;
    conv_body(fused_f, w_fal, b_fal, fused32, half * 512 + t * 2, og * 4, b, 128);
  }
}

// === prep_acts: upsample + cosine-sim + l2e partial + Q & V MFMA + transpose ====
// 512 threads (8 waves) per block, 8 ch/thread, o-tiles split 1-way (V) /
// 2-way (Q) per wave -> 16 waves/CU = 4 waves/SIMD for latency hiding.
__global__ __launch_bounds__(512, 4) void prep_acts(const float* __restrict__ edge32,
                                                    const float* __restrict__ fused32,
                                                    const float* __restrict__ sem,
                                                    const ushort_t* __restrict__ wqf,
                                                    const ushort_t* __restrict__ wff,
                                                    const float* __restrict__ b_q,
                                                    ushort_t* __restrict__ xt_sem,
                                                    ushort_t* __restrict__ xt_fused,
                                                    float* __restrict__ l2e,
                                                    float* __restrict__ dsum,
                                                    ushort_t* __restrict__ qtb,
                                                    ushort_t* __restrict__ v2b) {
  int b = blockIdx.y, bx = blockIdx.x;
  int y = bx >> 1, xh = (bx & 1) * 32;
  int t = threadIdx.x;                      // 0..511
  int nl = t & 31, cg = t >> 5;             // cg 0..15, 8 ch each
  int x = xh + nl;
  int yy0 = (y & 1) ? (y >> 1) : (y >> 1) - 1;
  float fy = (y & 1) ? 0.25f : 0.75f;
  int y0c = max(yy0, 0), y1c = min(yy0 + 1, 31);
  int xx0 = (x & 1) ? (x >> 1) : (x >> 1) - 1;
  float fx = (x & 1) ? 0.25f : 0.75f;
  int x0c = max(xx0, 0), x1c = min(xx0 + 1, 31);

  __shared__ uint_t se[32][68], ssm[32][68], sf[32][68];  // stride 68: 16B-aligned b128 rows
  __shared__ float red[8][3][32];
  __shared__ float simL[32];
  __shared__ ushort_t vstg[128 * 40];

  float ee = 0.f, ssum = 0.f, es = 0.f;
#pragma unroll
  for (int p = 0; p < 4; ++p) {           // channel pairs (4 pairs = 8 ch/thread)
    float evs[2], fvs[2], svs[2];
#pragma unroll
    for (int u = 0; u < 2; ++u) {
      int c = cg * 8 + p * 2 + u;
      const float* ip = edge32 + ((size_t)(b * 128 + c)) * 1024;
      float e00 = ip[y0c * 32 + x0c], e01 = ip[y0c * 32 + x1c];
      float e10 = ip[y1c * 32 + x0c], e11 = ip[y1c * 32 + x1c];
      float ev = (1.f - fy) * ((1.f - fx) * e00 + fx * e01) + fy * ((1.f - fx) * e10 + fx * e11);
      const float* fp = fused32 + ((size_t)(b * 128 + c)) * 1024;
      float f00 = fp[y0c * 32 + x0c], f01 = fp[y0c * 32 + x1c];
      float f10 = fp[y1c * 32 + x0c], f11 = fp[y1c * 32 + x1c];
      float fv = (1.f - fy) * ((1.f - fx) * f00 + fx * f01) + fy * ((1.f - fx) * f10 + fx * f11);
      float sv = sem[((size_t)(b * 128 + c)) * 4096 + y * 64 + x];
      ee += ev * ev; ssum += sv * sv; es += ev * sv;
      evs[u] = ev; fvs[u] = fv; svs[u] = sv;
    }
    int col = cg * 4 + p;
    se[nl][col]  = (uint_t)f2bf(evs[0]) | ((uint_t)f2bf(evs[1]) << 16);
    sf[nl][col]  = (uint_t)f2bf(fvs[0]) | ((uint_t)f2bf(fvs[1]) << 16);
    ssm[nl][col] = (uint_t)f2bf(svs[0]) | ((uint_t)f2bf(svs[1]) << 16);
  }
  ee += __shfl_xor(ee, 32, 64); ssum += __shfl_xor(ssum, 32, 64); es += __shfl_xor(es, 32, 64);
  int w = t >> 6, lane = t & 63;            // w 0..7
  int l15 = lane & 15, quad = lane >> 4;
  if (lane < 32) { red[w][0][lane] = ee; red[w][1][lane] = ssum; red[w][2][lane] = es; }
  __syncthreads();

  // bf16 n-major outputs (sem/fused only; edge never needed globally anymore)
  int base_n = b * 4096 + y * 64 + xh;
#pragma unroll
  for (int rep = 0; rep < 4; ++rep) {
    int d = rep * 512 + t;
    int r = d >> 6, cp = d & 63;
    ((uint_t*)xt_sem)[(size_t)(base_n + r) * 64 + cp] = ssm[r][cp];
    ((uint_t*)xt_fused)[(size_t)(base_n + r) * 64 + cp] = sf[r][cp];
  }
  if (t < 32) {
    float E = 0.f, S = 0.f, X = 0.f;
#pragma unroll
    for (int w2 = 0; w2 < 8; ++w2) { E += red[w2][0][t]; S += red[w2][1][t]; X += red[w2][2][t]; }
    float le = sqrtf(E), ls = sqrtf(S);
    float sv = (X / ((le + EPS) * (ls + EPS)) + 1.f) * 0.5f;
    simL[t] = sv;
    l2e[base_n + t] = le;
    float pe = expf(le - 16.f);       // fixed-shift softmax partial (exact reassociation)
#pragma unroll
    for (int m2 = 16; m2; m2 >>= 1) pe += __shfl_xor(pe, m2, 64);
    if (t == 0) atomicAdd(&dsum[b], pe);
  }
  __syncthreads();

  // ---- V = Wf @ [sem; fused] (MFMA); wave w owns o-tile w (8 tiles / 8 waves) ----
#pragma unroll
  for (int h = 0; h < 2; ++h) {
    f32x4 vacc = (f32x4){0.f,0.f,0.f,0.f};
#pragma unroll
    for (int kk = 0; kk < 4; ++kk) {
      bf16x8 bfr = *(const bf16x8*)&ssm[h * 16 + l15][kk * 16 + quad * 4];
      bf16x8 afr = *(const bf16x8*)(wff + (size_t)((w * 8 + kk) * 64 + lane) * 8);
      vacc = __builtin_amdgcn_mfma_f32_16x16x32_bf16(afr, bfr, vacc, 0, 0, 0);
    }
#pragma unroll
    for (int kk = 0; kk < 4; ++kk) {
      bf16x8 bfr = *(const bf16x8*)&sf[h * 16 + l15][kk * 16 + quad * 4];
      bf16x8 afr = *(const bf16x8*)(wff + (size_t)((w * 8 + 4 + kk) * 64 + lane) * 8);
      vacc = __builtin_amdgcn_mfma_f32_16x16x32_bf16(afr, bfr, vacc, 0, 0, 0);
    }
#pragma unroll
    for (int r = 0; r < 4; ++r) {
      int ch = w * 16 + quad * 4 + r;
      vstg[ch * 40 + h * 16 + l15] = f2bf(vacc[r]);
    }
  }

  // ---- Q = sim * (Wq_folded @ edge) + b_q (MFMA); wave w owns o-tiles w*2, w*2+1 ----
#pragma unroll
  for (int h = 0; h < 2; ++h) {
    f32x4 qacc[2];
#pragma unroll
    for (int i = 0; i < 2; ++i) qacc[i] = (f32x4){0.f,0.f,0.f,0.f};
#pragma unroll
    for (int kk = 0; kk < 4; ++kk) {
      bf16x8 bfr = *(const bf16x8*)&se[h * 16 + l15][kk * 16 + quad * 4];
#pragma unroll
      for (int i = 0; i < 2; ++i) {
        bf16x8 afr = *(const bf16x8*)(wqf + (size_t)(((w * 2 + i) * 4 + kk) * 64 + lane) * 8);
        qacc[i] = __builtin_amdgcn_mfma_f32_16x16x32_bf16(afr, bfr, qacc[i], 0, 0, 0);
      }
    }
    int px = h * 16 + l15;
    float sv = simL[px];
    int n = y * 64 + xh + px;
#pragma unroll
    for (int i = 0; i < 2; ++i) {
      int o = (w * 2 + i) * 16 + quad * 4;
      float4 bq = *(const float4*)(b_q + o);
      us4 pk = { f2bf(sv * qacc[i][0] + bq.x), f2bf(sv * qacc[i][1] + bq.y),
                 f2bf(sv * qacc[i][2] + bq.z), f2bf(sv * qacc[i][3] + bq.w) };
      *(us4*)(qtb + ((size_t)b * N + n) * 256 + o) = pk;
    }
  }

  __syncthreads();
  // coalesced v2b stores (padded ch-major); 512 threads cover 128 ch x 4 segs
  int np0 = y * PW + 8 + xh;
  {
    int ch = t >> 2, seg = t & 3;
    *(bf16x8*)(v2b + ((size_t)b * 128 + ch) * PIMG + np0 + seg * 8) =
        *(const bf16x8*)&vstg[ch * 40 + seg * 8];
  }
}

// ================= gemm_k: K projection, 16 queries/block, 1024 blocks ==========
__global__ __launch_bounds__(256, 4) void gemm_k(const ushort_t* __restrict__ xt_sem,
                                                 const ushort_t* __restrict__ xt_fused,
                                                 const ushort_t* __restrict__ wkf,
                                                 const float* __restrict__ b_k,
                                                 const float* __restrict__ l2e,
                                                 const float* __restrict__ dsum,
                                                 ushort_t* __restrict__ ktb) {
  int bx = blockIdx.x, bI = blockIdx.y;    // bx 0..255: 16-query group
  int t = threadIdx.x, w = t >> 6, lane = t & 63;
  int mrow = lane & 15, quad = lane >> 4;
  __shared__ __align__(16) ushort_t stg[16 * 264];

  int n0 = bx * 16, o0 = w * 64;
  float dscale = 4096.f / dsum[bI];
  const ushort_t* bS = xt_sem + ((size_t)bI * N + n0 + mrow) * 128 + quad * 8;
  const ushort_t* bF = xt_fused + ((size_t)bI * N + n0 + mrow) * 128 + quad * 8;
  f32x4 accL[4], accR[4];
#pragma unroll
  for (int i = 0; i < 4; ++i) { accL[i] = (f32x4){0.f,0.f,0.f,0.f}; accR[i] = (f32x4){0.f,0.f,0.f,0.f}; }
#pragma unroll
  for (int kk = 0; kk < 4; ++kk) {
    bf16x8 bfr = *(const bf16x8*)(bS + kk * 32);
#pragma unroll
    for (int i = 0; i < 4; ++i) {
      bf16x8 afr = *(const bf16x8*)(wkf + (size_t)((((w * 4 + i) * 8) + kk) * 64 + lane) * 8);
      accL[i] = __builtin_amdgcn_mfma_f32_16x16x32_bf16(afr, bfr, accL[i], 0, 0, 0);
    }
  }
#pragma unroll
  for (int kk = 0; kk < 4; ++kk) {
    bf16x8 bfr = *(const bf16x8*)(bF + kk * 32);
#pragma unroll
    for (int i = 0; i < 4; ++i) {
      bf16x8 afr = *(const bf16x8*)(wkf + (size_t)((((w * 4 + i) * 8) + 4 + kk) * 64 + lane) * 8);
      accR[i] = __builtin_amdgcn_mfma_f32_16x16x32_bf16(afr, bfr, accR[i], 0, 0, 0);
    }
  }
  int n = n0 + mrow;
  float dv = expf(l2e[bI * N + n] - 16.f) * dscale;
#pragma unroll
  for (int i = 0; i < 4; ++i) {
    int o = o0 + i * 16 + quad * 4;
    float4 bk = *(const float4*)(b_k + o);
    us4 pk = { f2bf(accL[i][0] * dv + accR[i][0] + bk.x),
               f2bf(accL[i][1] * dv + accR[i][1] + bk.y),
               f2bf(accL[i][2] * dv + accR[i][2] + bk.z),
               f2bf(accL[i][3] * dv + accR[i][3] + bk.w) };
    *(us4*)&stg[mrow * 264 + o] = pk;
  }
  __syncthreads();
  int np0 = (n0 >> 6) * PW + 8 + (n0 & 63);
#pragma unroll
  for (int r = 0; r < 2; ++r) {
    int cidx = r * 256 + t;
    int row = cidx >> 5, cc = cidx & 31;
    *(bf16x8*)(ktb + ((size_t)bI * PIMG + np0 + row) * 256 + cc * 8) =
        *(const bf16x8*)&stg[row * 264 + cc * 8];
  }
}

// ======== attention: R6 = 2x8 query tiles, 1024 blocks, 4 waves/SIMD ===========
// Each block is exactly the old subtile-0 (2 q-rows x 8 cols); grid doubles ->
// 4 blocks/CU (was 2) for 2x latency hiding on the K/V global loads. Removed
// enum rows contributed exact +0 before -> output bit-identical.
__global__ __launch_bounds__(256, 4) void attn_kernel(const ushort_t* __restrict__ qtb,
                                                      const ushort_t* __restrict__ ktb,
                                                      const ushort_t* __restrict__ v2b,
                                                      const float* __restrict__ b_fusion,
                                                      float* __restrict__ out) {
  // XCD swizzle: same (L & 7) -> same XCD; each XCD owns one (batch, y-half).
  int L = blockIdx.x;                          // 1024 blocks
  int xcd = L & 7, j = L >> 3;                 // j in [0,128)
  int b = xcd >> 1;
  int ty0 = (((xcd & 1) << 4) + (j >> 3)) * 2; // 32 y-tiles of 2 rows
  int tx0 = (j & 7) * 8;                       // 8 x-tiles of 8 cols
  int y0 = max(ty0 - 5, 0), y1 = min(ty0 + 6, 63);
  int nh = y1 - y0 + 1;                        // 7..12
  int xq0 = tx0 - 5, cb = tx0;                 // 18-wide QK window [tx0-5, tx0+12]
  int ntq = (nh * 18 + 15) >> 4;               // 16-key tiles over 18-wide enum, <= 14
  int npv = (nh * 3 + 3) >> 2;                 // 32-key PV chunks (24-wide enum), <= 9

  __shared__ ushort_t pst[16][288];            // P bf16 [q 16][key24], 576B rows
  __shared__ float reds[4][16];

  int t = threadIdx.x, w = t >> 6, lane = t & 63;
  int l15 = lane & 15, quad = lane >> 4;

  // full zero of pst: 16 rows x 144 u32; 256 threads x 9 u32, no divides
  {
    uint_t* pz = (uint_t*)&pst[t & 15][0] + (t >> 4) * 9;
#pragma unroll
    for (int cc = 0; cc < 9; ++cc) pz[cc] = 0;
  }

  // Q B-frags (2 rows x 8 cols), direct from qtb (held in regs)
  int n_s0 = (ty0 + (l15 >> 3)) * 64 + tx0 + (l15 & 7);
  bf16x8 qfr[8];
  {
    const ushort_t* q0 = qtb + ((size_t)b * N + n_s0) * 256 + quad * 8;
#pragma unroll
    for (int ks = 0; ks < 8; ++ks) qfr[ks] = *(const bf16x8*)(q0 + ks * 32);
  }
  int qx = tx0 + (l15 & 7);
  int qy0 = ty0 + (l15 >> 3);

  // ---- phase 1: QK^T over 18-wide enum; wave w: key-tiles w, w+4, ... ----
  const ushort_t* kb = ktb + (size_t)b * PIMG * 256;
  f32x4 sc[4];
#pragma unroll
  for (int i = 0; i < 4; ++i) {
    int tq = w + i * 4;
    if (tq >= ntq) break;
    int key = tq * 16 + l15;
    int ry = (key * 3641) >> 16;               // key / 18 (exact for key < 256)
    int rx = key - ry * 18;
    int yy = min(y0 + ry, 63);
    const ushort_t* krow = kb + (size_t)(yy * PW + cb + 3 + rx) * 256 + quad * 8;
    f32x4 a0 = (f32x4){0.f,0.f,0.f,0.f};
#pragma unroll
    for (int ks = 0; ks < 8; ++ks) {
      bf16x8 afr = *(const bf16x8*)(krow + ks * 32);
      a0 = __builtin_amdgcn_mfma_f32_16x16x32_bf16(afr, qfr[ks], a0, 0, 0, 0);
    }
    sc[i] = a0;
  }

  // ---- phase 2 (fused): mask + exp (fixed shift) + row-sum + P scatter ----
  float mysum = 0.f;
#pragma unroll
  for (int i = 0; i < 4; ++i) {
    int tq = w + i * 4;
    if (tq >= ntq) break;
#pragma unroll
    for (int r = 0; r < 4; ++r) {
      int key = tq * 16 + quad * 4 + r;
      int ry = (key * 3641) >> 16;
      int rx = key - ry * 18;
      int x = xq0 + rx;
      int dx = x - qx;
      bool xok = (dx >= -5) && (dx <= 5) && (x >= 0) && (x <= 63) && (ry < nh);
      int dy0 = y0 + ry - qy0;
      float e0 = (xok && dy0 >= -5 && dy0 <= 5) ? expf(sc[i][r] * 0.0625f) : 0.f;
      mysum += e0;
      if (ry < nh) {                           // guard: ry==12 enum tail would OOB
        int k24 = ry * 24 + rx + 3;            // max 11*24+20 = 284 < 288
        pst[l15][k24] = f2bf(e0);
      }
    }
  }
  mysum += __shfl_xor(mysum, 16, 64); mysum += __shfl_xor(mysum, 32, 64);
  if (quad == 0) reds[w][l15] = mysum;
  __syncthreads();

  float rinv = 1.f / (reds[0][l15] + reds[1][l15] + reds[2][l15] + reds[3][l15]);

  // ---- phase 3: PV. A = V (direct global b128) ----
  const ushort_t* vb = v2b + (size_t)b * 128 * PIMG;
#pragma unroll
  for (int half = 0; half < 2; ++half) {
    int ch0 = half * 64 + w * 16;
    const ushort_t* vrow = vb + (size_t)(ch0 + l15) * PIMG;
    f32x4 acc0 = (f32x4){0.f,0.f,0.f,0.f};
    for (int ks = 0; ks < npv; ++ks) {
      int kst = ks * 32 + quad * 8;            // never crosses a 24-key row
      int ry = (kst * 2731) >> 16;             // kst / 24
      int rxs = kst - ry * 24;
      int yy = min(y0 + ry, 63);
      bf16x8 av = *(const bf16x8*)(vrow + yy * PW + cb + rxs);
      bf16x8 bp0 = *(const bf16x8*)(&pst[l15][kst]);
      acc0 = __builtin_amdgcn_mfma_f32_16x16x32_bf16(av, bp0, acc0, 0, 0, 0);
    }
    int chg = ch0 + quad * 4;
    float4 bf4 = *(const float4*)(b_fusion + chg);
    float bfa[4] = {bf4.x, bf4.y, bf4.z, bf4.w};
#pragma unroll
    for (int r = 0; r < 4; ++r) {
      out[((size_t)b * 128 + chg + r) * N + n_s0] = acc0[r] * rinv + bfa[r];
    }
  }
}

extern "C" void kernel_launch(void* const* d_in, const int* in_sizes, int n_in,
                              void* d_out, int out_size, void* d_ws, size_t ws_size,
                              hipStream_t stream) {
  (void)in_sizes; (void)n_in; (void)out_size; (void)ws_size;
  const float* edge_f  = (const float*)d_in[0];
  const float* sem     = (const float*)d_in[1];
  const float* fused_f = (const float*)d_in[2];
  const float* w_align = (const float*)d_in[3];
  const float* b_align = (const float*)d_in[4];
  const float* w_fal   = (const float*)d_in[5];
  const float* b_fal   = (const float*)d_in[6];
  const float* w_q     = (const float*)d_in[7];
  const float* b_q     = (const float*)d_in[8];
  const float* w_k     = (const float*)d_in[9];
  const float* b_k     = (const float*)d_in[10];
  const float* w_fus   = (const float*)d_in[11];
  const float* b_fus   = (const float*)d_in[12];
  float* out = (float*)d_out;

  float* ws = (float*)d_ws;
  float* edge32   = ws;                              // 524288
  float* fused32  = ws + 524288;                     // 524288
  float* l2e      = ws + 1064960;                    // 16384
  float* dsum     = ws + 1081344;                    // 4 (+pad)
  ushort_t* xt_sem   = (ushort_t*)(ws + 1097728);    // 2097152 us
  ushort_t* xt_fused = (ushort_t*)(ws + 2146304);    // 2097152 us
  ushort_t* wqf      = (ushort_t*)(ws + 3194880);    // 32768 us (frag-order)
  ushort_t* wkf      = (ushort_t*)(ws + 3211264);    // 65536 us
  ushort_t* wff      = (ushort_t*)(ws + 3244032);    // 32768 us
  ushort_t* qtb      = (ushort_t*)(ws + 3260416);    // 4194304 us [b][n][256]
  ushort_t* ktb      = (ushort_t*)(ws + 5357568);    // 5242880 us [b][5120][256] padded
  ushort_t* v2b      = (ushort_t*)(ws + 7979008);    // 2621440 us [b][128][5120] padded
  // high-water ~37 MB (pad cols hold harness poison: finite bf16, masked in attn)

  prep_misc<<<576, 256, 0, stream>>>(edge_f, w_align, b_align, fused_f, w_fal, b_fal,
                                     w_q, w_k, w_fus, wqf, wkf, wff, edge32, fused32, dsum);
  prep_acts<<<dim3(128, NB), 512, 0, stream>>>(edge32, fused32, sem, wqf, wff, b_q,
                                               xt_sem, xt_fused, l2e, dsum, qtb, v2b);
  gemm_k<<<dim3(256, NB), 256, 0, stream>>>(xt_sem, xt_fused, wkf, b_k, l2e, dsum, ktb);
  attn_kernel<<<1024, 256, 0, stream>>>(qtb, ktb, v2b, b_fus, out);
}

// Round 8
// 152.033 us; speedup vs baseline: 1.0292x; 1.0292x over previous
//
#include <hip/hip_runtime.h>
#include <hip/hip_bf16.h>

#define NB 4
#define C 128
#define N 4096          // 64*64
#define EPS 1e-6f
#define PW 80           // padded image width (x in [-8, 71])
#define PIMG 5120       // 64*80 padded pixels per image

typedef float f32x4 __attribute__((ext_vector_type(4)));
typedef short bf16x8 __attribute__((ext_vector_type(8)));
typedef unsigned short ushort_t;
typedef unsigned int uint_t;

__device__ __forceinline__ ushort_t f2bf(float f) {
  __hip_bfloat16 h = __float2bfloat16(f);
  return *reinterpret_cast<ushort_t*>(&h);
}

struct alignas(8) us4 { ushort_t a, b, c, d; };

// ====== prep_misc: frag-order bf16 weights + both 32x32 convs + dsum zero ======
// conv threads own 2 px (float2) x 4 o-ch = 8 indep FMA chains per c-iter;
// weight reads are block-uniform (SGPR). FMA order per element bit-identical.
__device__ __forceinline__ void conv_body(const float* __restrict__ x,
                                          const float* __restrict__ w,
                                          const float* __restrict__ bias,
                                          float* __restrict__ out,
                                          int n0, int o0, int b, int CIN) {
  const float* xb = x + (size_t)(b * CIN) * 1024 + n0;
  float ax0 = 0.f, ay0 = 0.f, ax1 = 0.f, ay1 = 0.f;
  float ax2 = 0.f, ay2 = 0.f, ax3 = 0.f, ay3 = 0.f;
#pragma unroll 4
  for (int c = 0; c < CIN; ++c) {
    float2 xv = *(const float2*)(xb + (size_t)c * 1024);
    float w0 = w[(o0 + 0) * CIN + c];
    float w1 = w[(o0 + 1) * CIN + c];
    float w2 = w[(o0 + 2) * CIN + c];
    float w3 = w[(o0 + 3) * CIN + c];
    ax0 += w0 * xv.x; ay0 += w0 * xv.y;
    ax1 += w1 * xv.x; ay1 += w1 * xv.y;
    ax2 += w2 * xv.x; ay2 += w2 * xv.y;
    ax3 += w3 * xv.x; ay3 += w3 * xv.y;
  }
  size_t ob = ((size_t)b * 128 + o0) * 1024 + n0;
  float b0 = bias[o0], b1 = bias[o0 + 1], b2 = bias[o0 + 2], b3 = bias[o0 + 3];
  *(float2*)(out + ob)        = make_float2(ax0 + b0, ay0 + b0);
  *(float2*)(out + ob + 1024) = make_float2(ax1 + b1, ay1 + b1);
  *(float2*)(out + ob + 2048) = make_float2(ax2 + b2, ay2 + b2);
  *(float2*)(out + ob + 3072) = make_float2(ax3 + b3, ay3 + b3);
}

__global__ void prep_misc(const float* __restrict__ edge_f, const float* __restrict__ w_align,
                          const float* __restrict__ b_align,
                          const float* __restrict__ fused_f, const float* __restrict__ w_fal,
                          const float* __restrict__ b_fal,
                          const float* __restrict__ wq, const float* __restrict__ wk,
                          const float* __restrict__ wf,
                          ushort_t* __restrict__ wqf, ushort_t* __restrict__ wkf,
                          ushort_t* __restrict__ wff,
                          float* __restrict__ edge32, float* __restrict__ fused32,
                          float* __restrict__ dsum) {
  int bx = blockIdx.x, t = threadIdx.x;
  if (bx < 64) {
    if (bx == 0 && t < NB) dsum[t] = 0.f;
    int c = bx * 256 + t;                  // chunk id 0..16383
    int lane = c & 63;
    int mrow = lane & 15, quad = lane >> 4;
    if (c < 4096) {                        // wqf: 16 tiles x 4 kslots (K=128, concat folded)
      int grp = c >> 6;
      int tile = grp >> 2, kslot = grp & 3;
      int o = tile * 16 + mrow, k0 = kslot * 32 + quad * 8;
      const float* s = wq + o * 256 + k0;
      ushort_t* d = wqf + (size_t)c * 8;
#pragma unroll
      for (int j = 0; j < 8; ++j) d[j] = f2bf(s[j] + s[128 + j]);
    } else if (c < 12288) {                // wkf: 16 tiles x 8 kslots (K=256)
      int c2 = c - 4096;
      int grp = c2 >> 6;
      int tile = grp >> 3, kslot = grp & 7;
      int o = tile * 16 + mrow, k0 = kslot * 32 + quad * 8;
      const float* s = wk + o * 256 + k0;
      ushort_t* d = wkf + (size_t)c2 * 8;
#pragma unroll
      for (int j = 0; j < 8; ++j) d[j] = f2bf(s[j]);
    } else {                               // wff: 8 tiles x 8 kslots (K=256)
      int c2 = c - 12288;
      int grp = c2 >> 6;
      int tile = grp >> 3, kslot = grp & 7;
      int o = tile * 16 + mrow, k0 = kslot * 32 + quad * 8;
      const float* s = wf + o * 256 + k0;
      ushort_t* d = wff + (size_t)c2 * 8;
#pragma unroll
      for (int j = 0; j < 8; ++j) d[j] = f2bf(s[j]);
    }
  } else if (bx < 320) {
    int j = bx - 64;                       // edge conv: 256 blocks
    int b = j >> 6, rem = j & 63;
    int og = rem >> 1, half = rem & 1;
    conv_body(edge_f, w_align, b_align, edge32, half * 512 + t * 2, og * 4, b, 64);
  } else {
    int j = bx - 320;                      // fused conv: 256 blocks
    int b = j >> 6, rem = j & 63;
    int og = rem >> 1, half = rem & 1;
    conv_body(fused_f, w_fal, b_fal, fused32, half * 512 + t * 2, og * 4, b, 128);
  }
}

// === prep_acts: upsample + cosine-sim + l2e partial + Q & V MFMA + transpose ====
// 512 threads (8 waves) per block, 8 ch/thread, o-tiles split 1-way (V) /
// 2-way (Q) per wave -> 16 waves/CU = 4 waves/SIMD for latency hiding.
__global__ __launch_bounds__(512, 4) void prep_acts(const float* __restrict__ edge32,
                                                    const float* __restrict__ fused32,
                                                    const float* __restrict__ sem,
                                                    const ushort_t* __restrict__ wqf,
                                                    const ushort_t* __restrict__ wff,
                                                    const float* __restrict__ b_q,
                                                    ushort_t* __restrict__ xt_sem,
                                                    ushort_t* __restrict__ xt_fused,
                                                    float* __restrict__ l2e,
                                                    float* __restrict__ dsum,
                                                    ushort_t* __restrict__ qtb,
                                                    ushort_t* __restrict__ v2b) {
  int b = blockIdx.y, bx = blockIdx.x;
  int y = bx >> 1, xh = (bx & 1) * 32;
  int t = threadIdx.x;                      // 0..511
  int nl = t & 31, cg = t >> 5;             // cg 0..15, 8 ch each
  int x = xh + nl;
  int yy0 = (y & 1) ? (y >> 1) : (y >> 1) - 1;
  float fy = (y & 1) ? 0.25f : 0.75f;
  int y0c = max(yy0, 0), y1c = min(yy0 + 1, 31);
  int xx0 = (x & 1) ? (x >> 1) : (x >> 1) - 1;
  float fx = (x & 1) ? 0.25f : 0.75f;
  int x0c = max(xx0, 0), x1c = min(xx0 + 1, 31);

  __shared__ uint_t se[32][68], ssm[32][68], sf[32][68];  // stride 68: 16B-aligned b128 rows
  __shared__ float red[8][3][32];
  __shared__ float simL[32];
  __shared__ ushort_t vstg[128 * 40];

  float ee = 0.f, ssum = 0.f, es = 0.f;
#pragma unroll
  for (int p = 0; p < 4; ++p) {           // channel pairs (4 pairs = 8 ch/thread)
    float evs[2], fvs[2], svs[2];
#pragma unroll
    for (int u = 0; u < 2; ++u) {
      int c = cg * 8 + p * 2 + u;
      const float* ip = edge32 + ((size_t)(b * 128 + c)) * 1024;
      float e00 = ip[y0c * 32 + x0c], e01 = ip[y0c * 32 + x1c];
      float e10 = ip[y1c * 32 + x0c], e11 = ip[y1c * 32 + x1c];
      float ev = (1.f - fy) * ((1.f - fx) * e00 + fx * e01) + fy * ((1.f - fx) * e10 + fx * e11);
      const float* fp = fused32 + ((size_t)(b * 128 + c)) * 1024;
      float f00 = fp[y0c * 32 + x0c], f01 = fp[y0c * 32 + x1c];
      float f10 = fp[y1c * 32 + x0c], f11 = fp[y1c * 32 + x1c];
      float fv = (1.f - fy) * ((1.f - fx) * f00 + fx * f01) + fy * ((1.f - fx) * f10 + fx * f11);
      float sv = sem[((size_t)(b * 128 + c)) * 4096 + y * 64 + x];
      ee += ev * ev; ssum += sv * sv; es += ev * sv;
      evs[u] = ev; fvs[u] = fv; svs[u] = sv;
    }
    int col = cg * 4 + p;
    se[nl][col]  = (uint_t)f2bf(evs[0]) | ((uint_t)f2bf(evs[1]) << 16);
    sf[nl][col]  = (uint_t)f2bf(fvs[0]) | ((uint_t)f2bf(fvs[1]) << 16);
    ssm[nl][col] = (uint_t)f2bf(svs[0]) | ((uint_t)f2bf(svs[1]) << 16);
  }
  ee += __shfl_xor(ee, 32, 64); ssum += __shfl_xor(ssum, 32, 64); es += __shfl_xor(es, 32, 64);
  int w = t >> 6, lane = t & 63;            // w 0..7
  int l15 = lane & 15, quad = lane >> 4;
  if (lane < 32) { red[w][0][lane] = ee; red[w][1][lane] = ssum; red[w][2][lane] = es; }
  __syncthreads();

  // bf16 n-major outputs (sem/fused only; edge never needed globally anymore)
  int base_n = b * 4096 + y * 64 + xh;
#pragma unroll
  for (int rep = 0; rep < 4; ++rep) {
    int d = rep * 512 + t;
    int r = d >> 6, cp = d & 63;
    ((uint_t*)xt_sem)[(size_t)(base_n + r) * 64 + cp] = ssm[r][cp];
    ((uint_t*)xt_fused)[(size_t)(base_n + r) * 64 + cp] = sf[r][cp];
  }
  if (t < 32) {
    float E = 0.f, S = 0.f, X = 0.f;
#pragma unroll
    for (int w2 = 0; w2 < 8; ++w2) { E += red[w2][0][t]; S += red[w2][1][t]; X += red[w2][2][t]; }
    float le = sqrtf(E), ls = sqrtf(S);
    float sv = (X / ((le + EPS) * (ls + EPS)) + 1.f) * 0.5f;
    simL[t] = sv;
    l2e[base_n + t] = le;
    float pe = expf(le - 16.f);       // fixed-shift softmax partial (exact reassociation)
#pragma unroll
    for (int m2 = 16; m2; m2 >>= 1) pe += __shfl_xor(pe, m2, 64);
    if (t == 0) atomicAdd(&dsum[b], pe);
  }
  __syncthreads();

  // ---- V = Wf @ [sem; fused] (MFMA); wave w owns o-tile w (8 tiles / 8 waves) ----
#pragma unroll
  for (int h = 0; h < 2; ++h) {
    f32x4 vacc = (f32x4){0.f,0.f,0.f,0.f};
#pragma unroll
    for (int kk = 0; kk < 4; ++kk) {
      bf16x8 bfr = *(const bf16x8*)&ssm[h * 16 + l15][kk * 16 + quad * 4];
      bf16x8 afr = *(const bf16x8*)(wff + (size_t)((w * 8 + kk) * 64 + lane) * 8);
      vacc = __builtin_amdgcn_mfma_f32_16x16x32_bf16(afr, bfr, vacc, 0, 0, 0);
    }
#pragma unroll
    for (int kk = 0; kk < 4; ++kk) {
      bf16x8 bfr = *(const bf16x8*)&sf[h * 16 + l15][kk * 16 + quad * 4];
      bf16x8 afr = *(const bf16x8*)(wff + (size_t)((w * 8 + 4 + kk) * 64 + lane) * 8);
      vacc = __builtin_amdgcn_mfma_f32_16x16x32_bf16(afr, bfr, vacc, 0, 0, 0);
    }
#pragma unroll
    for (int r = 0; r < 4; ++r) {
      int ch = w * 16 + quad * 4 + r;
      vstg[ch * 40 + h * 16 + l15] = f2bf(vacc[r]);
    }
  }

  // ---- Q = sim * (Wq_folded @ edge) + b_q (MFMA); wave w owns o-tiles w*2, w*2+1 ----
#pragma unroll
  for (int h = 0; h < 2; ++h) {
    f32x4 qacc[2];
#pragma unroll
    for (int i = 0; i < 2; ++i) qacc[i] = (f32x4){0.f,0.f,0.f,0.f};
#pragma unroll
    for (int kk = 0; kk < 4; ++kk) {
      bf16x8 bfr = *(const bf16x8*)&se[h * 16 + l15][kk * 16 + quad * 4];
#pragma unroll
      for (int i = 0; i < 2; ++i) {
        bf16x8 afr = *(const bf16x8*)(wqf + (size_t)(((w * 2 + i) * 4 + kk) * 64 + lane) * 8);
        qacc[i] = __builtin_amdgcn_mfma_f32_16x16x32_bf16(afr, bfr, qacc[i], 0, 0, 0);
      }
    }
    int px = h * 16 + l15;
    float sv = simL[px];
    int n = y * 64 + xh + px;
#pragma unroll
    for (int i = 0; i < 2; ++i) {
      int o = (w * 2 + i) * 16 + quad * 4;
      float4 bq = *(const float4*)(b_q + o);
      us4 pk = { f2bf(sv * qacc[i][0] + bq.x), f2bf(sv * qacc[i][1] + bq.y),
                 f2bf(sv * qacc[i][2] + bq.z), f2bf(sv * qacc[i][3] + bq.w) };
      *(us4*)(qtb + ((size_t)b * N + n) * 256 + o) = pk;
    }
  }

  __syncthreads();
  // coalesced v2b stores (padded ch-major); 512 threads cover 128 ch x 4 segs
  int np0 = y * PW + 8 + xh;
  {
    int ch = t >> 2, seg = t & 3;
    *(bf16x8*)(v2b + ((size_t)b * 128 + ch) * PIMG + np0 + seg * 8) =
        *(const bf16x8*)&vstg[ch * 40 + seg * 8];
  }
}

// ================= gemm_k: K projection, 16 queries/block, 1024 blocks ==========
__global__ __launch_bounds__(256, 4) void gemm_k(const ushort_t* __restrict__ xt_sem,
                                                 const ushort_t* __restrict__ xt_fused,
                                                 const ushort_t* __restrict__ wkf,
                                                 const float* __restrict__ b_k,
                                                 const float* __restrict__ l2e,
                                                 const float* __restrict__ dsum,
                                                 ushort_t* __restrict__ ktb) {
  int bx = blockIdx.x, bI = blockIdx.y;    // bx 0..255: 16-query group
  int t = threadIdx.x, w = t >> 6, lane = t & 63;
  int mrow = lane & 15, quad = lane >> 4;
  __shared__ __align__(16) ushort_t stg[16 * 264];

  int n0 = bx * 16, o0 = w * 64;
  float dscale = 4096.f / dsum[bI];
  const ushort_t* bS = xt_sem + ((size_t)bI * N + n0 + mrow) * 128 + quad * 8;
  const ushort_t* bF = xt_fused + ((size_t)bI * N + n0 + mrow) * 128 + quad * 8;
  f32x4 accL[4], accR[4];
#pragma unroll
  for (int i = 0; i < 4; ++i) { accL[i] = (f32x4){0.f,0.f,0.f,0.f}; accR[i] = (f32x4){0.f,0.f,0.f,0.f}; }
#pragma unroll
  for (int kk = 0; kk < 4; ++kk) {
    bf16x8 bfr = *(const bf16x8*)(bS + kk * 32);
#pragma unroll
    for (int i = 0; i < 4; ++i) {
      bf16x8 afr = *(const bf16x8*)(wkf + (size_t)((((w * 4 + i) * 8) + kk) * 64 + lane) * 8);
      accL[i] = __builtin_amdgcn_mfma_f32_16x16x32_bf16(afr, bfr, accL[i], 0, 0, 0);
    }
  }
#pragma unroll
  for (int kk = 0; kk < 4; ++kk) {
    bf16x8 bfr = *(const bf16x8*)(bF + kk * 32);
#pragma unroll
    for (int i = 0; i < 4; ++i) {
      bf16x8 afr = *(const bf16x8*)(wkf + (size_t)((((w * 4 + i) * 8) + 4 + kk) * 64 + lane) * 8);
      accR[i] = __builtin_amdgcn_mfma_f32_16x16x32_bf16(afr, bfr, accR[i], 0, 0, 0);
    }
  }
  int n = n0 + mrow;
  float dv = expf(l2e[bI * N + n] - 16.f) * dscale;
#pragma unroll
  for (int i = 0; i < 4; ++i) {
    int o = o0 + i * 16 + quad * 4;
    float4 bk = *(const float4*)(b_k + o);
    us4 pk = { f2bf(accL[i][0] * dv + accR[i][0] + bk.x),
               f2bf(accL[i][1] * dv + accR[i][1] + bk.y),
               f2bf(accL[i][2] * dv + accR[i][2] + bk.z),
               f2bf(accL[i][3] * dv + accR[i][3] + bk.w) };
    *(us4*)&stg[mrow * 264 + o] = pk;
  }
  __syncthreads();
  int np0 = (n0 >> 6) * PW + 8 + (n0 & 63);
#pragma unroll
  for (int r = 0; r < 2; ++r) {
    int cidx = r * 256 + t;
    int row = cidx >> 5, cc = cidx & 31;
    *(bf16x8*)(ktb + ((size_t)bI * PIMG + np0 + row) * 256 + cc * 8) =
        *(const bf16x8*)&stg[row * 264 + cc * 8];
  }
}

// ======== attention: R7 = R5 geometry (512 blocks, 8x4 tiles, 2 subtiles,
// 18-wide window) but 512 threads / 8 waves per block: key-tiles split over
// 8 waves (tq = w + i*8), PV one 16-ch slice per wave. Traffic identical to
// R5; waves/SIMD 2 -> 4 to hide K/V load latency.
__global__ __launch_bounds__(512, 2) void attn_kernel(const ushort_t* __restrict__ qtb,
                                                      const ushort_t* __restrict__ ktb,
                                                      const ushort_t* __restrict__ v2b,
                                                      const float* __restrict__ b_fusion,
                                                      float* __restrict__ out) {
  // XCD swizzle: same (L & 7) -> same XCD; each XCD owns one (batch, y-half-band).
  int L = blockIdx.x;                          // 512 blocks
  int xcd = L & 7, j = L >> 3;                 // j in [0,64)
  int b = xcd >> 1;
  int ty0 = (((xcd & 1) << 3) + (j >> 3)) * 4; // 16 y-tiles of 4 rows
  int tx0 = (j & 7) * 8;                       // 8 x-tiles of 8 cols
  int y0 = max(ty0 - 5, 0), y1 = min(ty0 + 8, 63);
  int nh = y1 - y0 + 1;                        // 9..14
  int xq0 = tx0 - 5, cb = tx0;                 // 18-wide QK window [tx0-5, tx0+12]
  int ntq = (nh * 18 + 15) >> 4;               // 16-key tiles over 18-wide enum, <= 16
  int npv = (nh * 3 + 3) >> 2;                 // 32-key PV chunks (24-wide enum), <= 11

  __shared__ ushort_t pst[32][352];            // P bf16 [q 32][key24], 704B rows
  __shared__ float reds[8][2][16];

  int t = threadIdx.x, w = t >> 6, lane = t & 63;   // w 0..7
  int l15 = lane & 15, quad = lane >> 4;

  // full zero of pst: 32 rows x 176 u32; 512 threads x 11 u32, no divides
  {
    uint_t* pr = (uint_t*)&pst[t & 31][0] + (t >> 5) * 11;
#pragma unroll
    for (int cc = 0; cc < 11; ++cc) pr[cc] = 0;
  }

  // Q B-frags for both 8x2 subtiles, direct from qtb (held in regs)
  int n_s0 = (ty0 + (l15 >> 3)) * 64 + tx0 + (l15 & 7);
  int n_s1 = n_s0 + 128;                       // +2 rows
  bf16x8 qfr[2][8];
  {
    const ushort_t* q0 = qtb + ((size_t)b * N + n_s0) * 256 + quad * 8;
    const ushort_t* q1 = qtb + ((size_t)b * N + n_s1) * 256 + quad * 8;
#pragma unroll
    for (int ks = 0; ks < 8; ++ks) {
      qfr[0][ks] = *(const bf16x8*)(q0 + ks * 32);
      qfr[1][ks] = *(const bf16x8*)(q1 + ks * 32);
    }
  }
  int qx = tx0 + (l15 & 7);
  int qy0 = ty0 + (l15 >> 3);                  // subtile 0; subtile 1 = +2

  // ---- phase 1: QK^T over 18-wide enum; wave w: key-tiles w, w+8 ----
  const ushort_t* kb = ktb + (size_t)b * PIMG * 256;
  f32x4 sc[2][2];
#pragma unroll
  for (int i = 0; i < 2; ++i) {
    int tq = w + i * 8;
    if (tq >= ntq) break;
    int key = tq * 16 + l15;
    int ry = (key * 3641) >> 16;               // key / 18 (exact for key < 256)
    int rx = key - ry * 18;
    int yy = min(y0 + ry, 63);
    const ushort_t* krow = kb + (size_t)(yy * PW + cb + 3 + rx) * 256 + quad * 8;
    f32x4 a0 = (f32x4){0.f,0.f,0.f,0.f}, a1 = (f32x4){0.f,0.f,0.f,0.f};
#pragma unroll
    for (int ks = 0; ks < 8; ++ks) {
      bf16x8 afr = *(const bf16x8*)(krow + ks * 32);
      a0 = __builtin_amdgcn_mfma_f32_16x16x32_bf16(afr, qfr[0][ks], a0, 0, 0, 0);
      a1 = __builtin_amdgcn_mfma_f32_16x16x32_bf16(afr, qfr[1][ks], a1, 0, 0, 0);
    }
    sc[i][0] = a0; sc[i][1] = a1;
  }

  // ---- phase 2 (fused): mask + exp (fixed shift) + row-sum + P scatter ----
  float mysum0 = 0.f, mysum1 = 0.f;
#pragma unroll
  for (int i = 0; i < 2; ++i) {
    int tq = w + i * 8;
    if (tq >= ntq) break;
#pragma unroll
    for (int r = 0; r < 4; ++r) {
      int key = tq * 16 + quad * 4 + r;
      int ry = (key * 3641) >> 16;
      int rx = key - ry * 18;
      int x = xq0 + rx;
      int dx = x - qx;
      bool xok = (dx >= -5) && (dx <= 5) && (x >= 0) && (x <= 63) && (ry < nh);
      int dy0 = y0 + ry - qy0;
      float e0 = (xok && dy0 >= -5 && dy0 <= 5) ? expf(sc[i][0][r] * 0.0625f) : 0.f;
      int dy1 = dy0 - 2;
      float e1 = (xok && dy1 >= -5 && dy1 <= 5) ? expf(sc[i][1][r] * 0.0625f) : 0.f;
      mysum0 += e0; mysum1 += e1;
      int k24 = ry * 24 + rx + 3;              // max 342 < 352, in-bounds
      pst[l15][k24]      = f2bf(e0);
      pst[16 + l15][k24] = f2bf(e1);
    }
  }
  mysum0 += __shfl_xor(mysum0, 16, 64); mysum0 += __shfl_xor(mysum0, 32, 64);
  mysum1 += __shfl_xor(mysum1, 16, 64); mysum1 += __shfl_xor(mysum1, 32, 64);
  if (quad == 0) { reds[w][0][l15] = mysum0; reds[w][1][l15] = mysum1; }
  __syncthreads();

  float rinv0 = 1.f / (reds[0][0][l15] + reds[1][0][l15] + reds[2][0][l15] + reds[3][0][l15] +
                       reds[4][0][l15] + reds[5][0][l15] + reds[6][0][l15] + reds[7][0][l15]);
  float rinv1 = 1.f / (reds[0][1][l15] + reds[1][1][l15] + reds[2][1][l15] + reds[3][1][l15] +
                       reds[4][1][l15] + reds[5][1][l15] + reds[6][1][l15] + reds[7][1][l15]);

  // ---- phase 3: PV. A = V (direct global b128); wave w owns 16 channels ----
  const ushort_t* vb = v2b + (size_t)b * 128 * PIMG;
  {
    int ch0 = w * 16;
    const ushort_t* vrow = vb + (size_t)(ch0 + l15) * PIMG;
    f32x4 acc0 = (f32x4){0.f,0.f,0.f,0.f}, acc1 = (f32x4){0.f,0.f,0.f,0.f};
    for (int ks = 0; ks < npv; ++ks) {
      int kst = ks * 32 + quad * 8;            // never crosses a 24-key row
      int ry = (kst * 2731) >> 16;             // kst / 24
      int rxs = kst - ry * 24;
      int yy = min(y0 + ry, 63);
      bf16x8 av = *(const bf16x8*)(vrow + yy * PW + cb + rxs);
      bf16x8 bp0 = *(const bf16x8*)(&pst[l15][kst]);
      bf16x8 bp1 = *(const bf16x8*)(&pst[16 + l15][kst]);
      acc0 = __builtin_amdgcn_mfma_f32_16x16x32_bf16(av, bp0, acc0, 0, 0, 0);
      acc1 = __builtin_amdgcn_mfma_f32_16x16x32_bf16(av, bp1, acc1, 0, 0, 0);
    }
    int chg = ch0 + quad * 4;
    float4 bf4 = *(const float4*)(b_fusion + chg);
    float bfa[4] = {bf4.x, bf4.y, bf4.z, bf4.w};
#pragma unroll
    for (int r = 0; r < 4; ++r) {
      out[((size_t)b * 128 + chg + r) * N + n_s0] = acc0[r] * rinv0 + bfa[r];
      out[((size_t)b * 128 + chg + r) * N + n_s1] = acc1[r] * rinv1 + bfa[r];
    }
  }
}

extern "C" void kernel_launch(void* const* d_in, const int* in_sizes, int n_in,
                              void* d_out, int out_size, void* d_ws, size_t ws_size,
                              hipStream_t stream) {
  (void)in_sizes; (void)n_in; (void)out_size; (void)ws_size;
  const float* edge_f  = (const float*)d_in[0];
  const float* sem     = (const float*)d_in[1];
  const float* fused_f = (const float*)d_in[2];
  const float* w_align = (const float*)d_in[3];
  const float* b_align = (const float*)d_in[4];
  const float* w_fal   = (const float*)d_in[5];
  const float* b_fal   = (const float*)d_in[6];
  const float* w_q     = (const float*)d_in[7];
  const float* b_q     = (const float*)d_in[8];
  const float* w_k     = (const float*)d_in[9];
  const float* b_k     = (const float*)d_in[10];
  const float* w_fus   = (const float*)d_in[11];
  const float* b_fus   = (const float*)d_in[12];
  float* out = (float*)d_out;

  float* ws = (float*)d_ws;
  float* edge32   = ws;                              // 524288
  float* fused32  = ws + 524288;                     // 524288
  float* l2e      = ws + 1064960;                    // 16384
  float* dsum     = ws + 1081344;                    // 4 (+pad)
  ushort_t* xt_sem   = (ushort_t*)(ws + 1097728);    // 2097152 us
  ushort_t* xt_fused = (ushort_t*)(ws + 2146304);    // 2097152 us
  ushort_t* wqf      = (ushort_t*)(ws + 3194880);    // 32768 us (frag-order)
  ushort_t* wkf      = (ushort_t*)(ws + 3211264);    // 65536 us
  ushort_t* wff      = (ushort_t*)(ws + 3244032);    // 32768 us
  ushort_t* qtb      = (ushort_t*)(ws + 3260416);    // 4194304 us [b][n][256]
  ushort_t* ktb      = (ushort_t*)(ws + 5357568);    // 5242880 us [b][5120][256] padded
  ushort_t* v2b      = (ushort_t*)(ws + 7979008);    // 2621440 us [b][128][5120] padded
  // high-water ~37 MB (pad cols hold harness poison: finite bf16, masked in attn)

  prep_misc<<<576, 256, 0, stream>>>(edge_f, w_align, b_align, fused_f, w_fal, b_fal,
                                     w_q, w_k, w_fus, wqf, wkf, wff, edge32, fused32, dsum);
  prep_acts<<<dim3(128, NB), 512, 0, stream>>>(edge32, fused32, sem, wqf, wff, b_q,
                                               xt_sem, xt_fused, l2e, dsum, qtb, v2b);
  gemm_k<<<dim3(256, NB), 256, 0, stream>>>(xt_sem, xt_fused, wkf, b_k, l2e, dsum, ktb);
  attn_kernel<<<512, 512, 0, stream>>>(qtb, ktb, v2b, b_fus, out);
}

// Round 9
// 150.340 us; speedup vs baseline: 1.0408x; 1.0113x over previous
//
#include <hip/hip_runtime.h>
#include <hip/hip_bf16.h>

#define NB 4
#define C 128
#define N 4096          // 64*64
#define EPS 1e-6f
#define PW 80           // padded image width (x in [-8, 71])
#define PIMG 5120       // 64*80 padded pixels per image

typedef float f32x4 __attribute__((ext_vector_type(4)));
typedef short bf16x8 __attribute__((ext_vector_type(8)));
typedef unsigned short ushort_t;
typedef unsigned int uint_t;

__device__ __forceinline__ ushort_t f2bf(float f) {
  __hip_bfloat16 h = __float2bfloat16(f);
  return *reinterpret_cast<ushort_t*>(&h);
}

struct alignas(8) us4 { ushort_t a, b, c, d; };

// ====== prep_misc: frag-order bf16 weights + both 32x32 convs + dsum zero ======
__device__ __forceinline__ void conv_body(const float* __restrict__ x,
                                          const float* __restrict__ w,
                                          const float* __restrict__ bias,
                                          float* __restrict__ out,
                                          int n0, int o0, int b, int CIN) {
  const float* xb = x + (size_t)(b * CIN) * 1024 + n0;
  float ax0 = 0.f, ay0 = 0.f, ax1 = 0.f, ay1 = 0.f;
  float ax2 = 0.f, ay2 = 0.f, ax3 = 0.f, ay3 = 0.f;
#pragma unroll 4
  for (int c = 0; c < CIN; ++c) {
    float2 xv = *(const float2*)(xb + (size_t)c * 1024);
    float w0 = w[(o0 + 0) * CIN + c];
    float w1 = w[(o0 + 1) * CIN + c];
    float w2 = w[(o0 + 2) * CIN + c];
    float w3 = w[(o0 + 3) * CIN + c];
    ax0 += w0 * xv.x; ay0 += w0 * xv.y;
    ax1 += w1 * xv.x; ay1 += w1 * xv.y;
    ax2 += w2 * xv.x; ay2 += w2 * xv.y;
    ax3 += w3 * xv.x; ay3 += w3 * xv.y;
  }
  size_t ob = ((size_t)b * 128 + o0) * 1024 + n0;
  float b0 = bias[o0], b1 = bias[o0 + 1], b2 = bias[o0 + 2], b3 = bias[o0 + 3];
  *(float2*)(out + ob)        = make_float2(ax0 + b0, ay0 + b0);
  *(float2*)(out + ob + 1024) = make_float2(ax1 + b1, ay1 + b1);
  *(float2*)(out + ob + 2048) = make_float2(ax2 + b2, ay2 + b2);
  *(float2*)(out + ob + 3072) = make_float2(ax3 + b3, ay3 + b3);
}

__global__ void prep_misc(const float* __restrict__ edge_f, const float* __restrict__ w_align,
                          const float* __restrict__ b_align,
                          const float* __restrict__ fused_f, const float* __restrict__ w_fal,
                          const float* __restrict__ b_fal,
                          const float* __restrict__ wq, const float* __restrict__ wk,
                          const float* __restrict__ wf,
                          ushort_t* __restrict__ wqf, ushort_t* __restrict__ wkf,
                          ushort_t* __restrict__ wff,
                          float* __restrict__ edge32, float* __restrict__ fused32,
                          float* __restrict__ dsum) {
  int bx = blockIdx.x, t = threadIdx.x;
  if (bx < 64) {
    if (bx == 0 && t < NB) dsum[t] = 0.f;
    int c = bx * 256 + t;                  // chunk id 0..16383
    int lane = c & 63;
    int mrow = lane & 15, quad = lane >> 4;
    if (c < 4096) {                        // wqf: 16 tiles x 4 kslots (K=128, concat folded)
      int grp = c >> 6;
      int tile = grp >> 2, kslot = grp & 3;
      int o = tile * 16 + mrow, k0 = kslot * 32 + quad * 8;
      const float* s = wq + o * 256 + k0;
      ushort_t* d = wqf + (size_t)c * 8;
#pragma unroll
      for (int j = 0; j < 8; ++j) d[j] = f2bf(s[j] + s[128 + j]);
    } else if (c < 12288) {                // wkf: 16 tiles x 8 kslots (K=256)
      int c2 = c - 4096;
      int grp = c2 >> 6;
      int tile = grp >> 3, kslot = grp & 7;
      int o = tile * 16 + mrow, k0 = kslot * 32 + quad * 8;
      const float* s = wk + o * 256 + k0;
      ushort_t* d = wkf + (size_t)c2 * 8;
#pragma unroll
      for (int j = 0; j < 8; ++j) d[j] = f2bf(s[j]);
    } else {                               // wff: 8 tiles x 8 kslots (K=256)
      int c2 = c - 12288;
      int grp = c2 >> 6;
      int tile = grp >> 3, kslot = grp & 7;
      int o = tile * 16 + mrow, k0 = kslot * 32 + quad * 8;
      const float* s = wf + o * 256 + k0;
      ushort_t* d = wff + (size_t)c2 * 8;
#pragma unroll
      for (int j = 0; j < 8; ++j) d[j] = f2bf(s[j]);
    }
  } else if (bx < 320) {
    int j = bx - 64;                       // edge conv: 256 blocks
    int b = j >> 6, rem = j & 63;
    int og = rem >> 1, half = rem & 1;
    conv_body(edge_f, w_align, b_align, edge32, half * 512 + t * 2, og * 4, b, 64);
  } else {
    int j = bx - 320;                      // fused conv: 256 blocks
    int b = j >> 6, rem = j & 63;
    int og = rem >> 1, half = rem & 1;
    conv_body(fused_f, w_fal, b_fal, fused32, half * 512 + t * 2, og * 4, b, 128);
  }
}

// ====== l2ek: edge-bilinear ||.||2 + exp partial -> dsum (tiny, L2-hot) ========
// Bit-exact replica of the old per-unit dsum partial sequence (verified R3).
// Runs before prep_acts so K's density scale is available without gemm_k.
__global__ __launch_bounds__(512) void l2ek(const float* __restrict__ edge32,
                                            float* __restrict__ dsum) {
  int b = blockIdx.y, bx = blockIdx.x;
  int y = bx >> 1, xh = (bx & 1) * 32;
  int t = threadIdx.x;
  int nl = t & 31, cg = t >> 5;
  int x = xh + nl;
  int yy0 = (y & 1) ? (y >> 1) : (y >> 1) - 1;
  float fy = (y & 1) ? 0.25f : 0.75f;
  int y0c = max(yy0, 0), y1c = min(yy0 + 1, 31);
  int xx0 = (x & 1) ? (x >> 1) : (x >> 1) - 1;
  float fx = (x & 1) ? 0.25f : 0.75f;
  int x0c = max(xx0, 0), x1c = min(xx0 + 1, 31);

  __shared__ float red[8][32];
  float ee = 0.f;
#pragma unroll
  for (int p = 0; p < 4; ++p) {
#pragma unroll
    for (int u = 0; u < 2; ++u) {
      int c = cg * 8 + p * 2 + u;
      const float* ip = edge32 + ((size_t)(b * 128 + c)) * 1024;
      float e00 = ip[y0c * 32 + x0c], e01 = ip[y0c * 32 + x1c];
      float e10 = ip[y1c * 32 + x0c], e11 = ip[y1c * 32 + x1c];
      float ev = (1.f - fy) * ((1.f - fx) * e00 + fx * e01) + fy * ((1.f - fx) * e10 + fx * e11);
      ee += ev * ev;
    }
  }
  ee += __shfl_xor(ee, 32, 64);
  int w = t >> 6, lane = t & 63;
  if (lane < 32) red[w][lane] = ee;
  __syncthreads();
  if (t < 32) {
    float E = 0.f;
#pragma unroll
    for (int w2 = 0; w2 < 8; ++w2) E += red[w2][t];
    float le = sqrtf(E);
    float pe = expf(le - 16.f);
#pragma unroll
    for (int m2 = 16; m2; m2 >>= 1) pe += __shfl_xor(pe, m2, 64);
    if (t == 0) atomicAdd(&dsum[b], pe);
  }
}

// === prep_acts: upsample + cos-sim + Q & K & V MFMA, all direct stores ========
// R8: K folded in (dsum ready via l2ek). No kstg staging — K stores us4
// direct to ktb exactly like Q does to qtb (R3's occupancy mistake fixed).
// gemm_k + xt_sem/xt_fused round-trip deleted. LDS ~39.6 KB (unchanged).
__global__ __launch_bounds__(512, 4) void prep_acts(const float* __restrict__ edge32,
                                                    const float* __restrict__ fused32,
                                                    const float* __restrict__ sem,
                                                    const ushort_t* __restrict__ wqf,
                                                    const ushort_t* __restrict__ wkf,
                                                    const ushort_t* __restrict__ wff,
                                                    const float* __restrict__ b_q,
                                                    const float* __restrict__ b_k,
                                                    const float* __restrict__ dsum,
                                                    ushort_t* __restrict__ qtb,
                                                    ushort_t* __restrict__ ktb,
                                                    ushort_t* __restrict__ v2b) {
  int b = blockIdx.y, bx = blockIdx.x;
  int y = bx >> 1, xh = (bx & 1) * 32;
  int t = threadIdx.x;                      // 0..511
  int nl = t & 31, cg = t >> 5;             // cg 0..15, 8 ch each
  int x = xh + nl;
  int yy0 = (y & 1) ? (y >> 1) : (y >> 1) - 1;
  float fy = (y & 1) ? 0.25f : 0.75f;
  int y0c = max(yy0, 0), y1c = min(yy0 + 1, 31);
  int xx0 = (x & 1) ? (x >> 1) : (x >> 1) - 1;
  float fx = (x & 1) ? 0.25f : 0.75f;
  int x0c = max(xx0, 0), x1c = min(xx0 + 1, 31);

  __shared__ uint_t se[32][68], ssm[32][68], sf[32][68];  // stride 68: 16B-aligned b128 rows
  __shared__ float red[8][3][32];
  __shared__ float simL[32], l2eL[32];
  __shared__ ushort_t vstg[128 * 40];

  float dscale = 4096.f / dsum[b];          // l2ek completed before this kernel

  float ee = 0.f, ssum = 0.f, es = 0.f;
#pragma unroll
  for (int p = 0; p < 4; ++p) {           // channel pairs (4 pairs = 8 ch/thread)
    float evs[2], fvs[2], svs[2];
#pragma unroll
    for (int u = 0; u < 2; ++u) {
      int c = cg * 8 + p * 2 + u;
      const float* ip = edge32 + ((size_t)(b * 128 + c)) * 1024;
      float e00 = ip[y0c * 32 + x0c], e01 = ip[y0c * 32 + x1c];
      float e10 = ip[y1c * 32 + x0c], e11 = ip[y1c * 32 + x1c];
      float ev = (1.f - fy) * ((1.f - fx) * e00 + fx * e01) + fy * ((1.f - fx) * e10 + fx * e11);
      const float* fp = fused32 + ((size_t)(b * 128 + c)) * 1024;
      float f00 = fp[y0c * 32 + x0c], f01 = fp[y0c * 32 + x1c];
      float f10 = fp[y1c * 32 + x0c], f11 = fp[y1c * 32 + x1c];
      float fv = (1.f - fy) * ((1.f - fx) * f00 + fx * f01) + fy * ((1.f - fx) * f10 + fx * f11);
      float sv = sem[((size_t)(b * 128 + c)) * 4096 + y * 64 + x];
      ee += ev * ev; ssum += sv * sv; es += ev * sv;
      evs[u] = ev; fvs[u] = fv; svs[u] = sv;
    }
    int col = cg * 4 + p;
    se[nl][col]  = (uint_t)f2bf(evs[0]) | ((uint_t)f2bf(evs[1]) << 16);
    sf[nl][col]  = (uint_t)f2bf(fvs[0]) | ((uint_t)f2bf(fvs[1]) << 16);
    ssm[nl][col] = (uint_t)f2bf(svs[0]) | ((uint_t)f2bf(svs[1]) << 16);
  }
  ee += __shfl_xor(ee, 32, 64); ssum += __shfl_xor(ssum, 32, 64); es += __shfl_xor(es, 32, 64);
  int w = t >> 6, lane = t & 63;            // w 0..7
  int l15 = lane & 15, quad = lane >> 4;
  if (lane < 32) { red[w][0][lane] = ee; red[w][1][lane] = ssum; red[w][2][lane] = es; }
  __syncthreads();

  if (t < 32) {
    float E = 0.f, S = 0.f, X = 0.f;
#pragma unroll
    for (int w2 = 0; w2 < 8; ++w2) { E += red[w2][0][t]; S += red[w2][1][t]; X += red[w2][2][t]; }
    float le = sqrtf(E), ls = sqrtf(S);
    float sv = (X / ((le + EPS) * (ls + EPS)) + 1.f) * 0.5f;
    simL[t] = sv;
    l2eL[t] = le;
  }
  __syncthreads();

  int np0 = y * PW + 8 + xh;

  // ---- V = Wf @ [sem; fused] (MFMA); wave w owns o-tile w ----
#pragma unroll
  for (int h = 0; h < 2; ++h) {
    f32x4 vacc = (f32x4){0.f,0.f,0.f,0.f};
#pragma unroll
    for (int kk = 0; kk < 4; ++kk) {
      bf16x8 bfr = *(const bf16x8*)&ssm[h * 16 + l15][kk * 16 + quad * 4];
      bf16x8 afr = *(const bf16x8*)(wff + (size_t)((w * 8 + kk) * 64 + lane) * 8);
      vacc = __builtin_amdgcn_mfma_f32_16x16x32_bf16(afr, bfr, vacc, 0, 0, 0);
    }
#pragma unroll
    for (int kk = 0; kk < 4; ++kk) {
      bf16x8 bfr = *(const bf16x8*)&sf[h * 16 + l15][kk * 16 + quad * 4];
      bf16x8 afr = *(const bf16x8*)(wff + (size_t)((w * 8 + 4 + kk) * 64 + lane) * 8);
      vacc = __builtin_amdgcn_mfma_f32_16x16x32_bf16(afr, bfr, vacc, 0, 0, 0);
    }
#pragma unroll
    for (int r = 0; r < 4; ++r) {
      int ch = w * 16 + quad * 4 + r;
      vstg[ch * 40 + h * 16 + l15] = f2bf(vacc[r]);
    }
  }

  // ---- K = dv * (WkL @ sem) + (WkR @ fused) + b_k; wave w: o-tiles w*2,w*2+1;
  //      direct us4 stores to ktb (same [pixel][256] layout as old gemm_k) ----
#pragma unroll
  for (int h = 0; h < 2; ++h) {
    f32x4 aL[2], aR[2];
#pragma unroll
    for (int i = 0; i < 2; ++i) { aL[i] = (f32x4){0.f,0.f,0.f,0.f}; aR[i] = (f32x4){0.f,0.f,0.f,0.f}; }
#pragma unroll
    for (int kk = 0; kk < 4; ++kk) {
      bf16x8 bfr = *(const bf16x8*)&ssm[h * 16 + l15][kk * 16 + quad * 4];
#pragma unroll
      for (int i = 0; i < 2; ++i) {
        bf16x8 afr = *(const bf16x8*)(wkf + (size_t)((((w * 2 + i) * 8) + kk) * 64 + lane) * 8);
        aL[i] = __builtin_amdgcn_mfma_f32_16x16x32_bf16(afr, bfr, aL[i], 0, 0, 0);
      }
    }
#pragma unroll
    for (int kk = 0; kk < 4; ++kk) {
      bf16x8 bfr = *(const bf16x8*)&sf[h * 16 + l15][kk * 16 + quad * 4];
#pragma unroll
      for (int i = 0; i < 2; ++i) {
        bf16x8 afr = *(const bf16x8*)(wkf + (size_t)((((w * 2 + i) * 8) + 4 + kk) * 64 + lane) * 8);
        aR[i] = __builtin_amdgcn_mfma_f32_16x16x32_bf16(afr, bfr, aR[i], 0, 0, 0);
      }
    }
    float dv = expf(l2eL[h * 16 + l15] - 16.f) * dscale;
    size_t krowo = ((size_t)b * PIMG + np0 + h * 16 + l15) * 256;
#pragma unroll
    for (int i = 0; i < 2; ++i) {
      int o = (w * 2 + i) * 16 + quad * 4;
      float4 bk4 = *(const float4*)(b_k + o);
      us4 pk = { f2bf(aL[i][0] * dv + aR[i][0] + bk4.x),
                 f2bf(aL[i][1] * dv + aR[i][1] + bk4.y),
                 f2bf(aL[i][2] * dv + aR[i][2] + bk4.z),
                 f2bf(aL[i][3] * dv + aR[i][3] + bk4.w) };
      *(us4*)(ktb + krowo + o) = pk;
    }
  }

  // ---- Q = sim * (Wq_folded @ edge) + b_q; wave w: o-tiles w*2,w*2+1 ----
#pragma unroll
  for (int h = 0; h < 2; ++h) {
    f32x4 qacc[2];
#pragma unroll
    for (int i = 0; i < 2; ++i) qacc[i] = (f32x4){0.f,0.f,0.f,0.f};
#pragma unroll
    for (int kk = 0; kk < 4; ++kk) {
      bf16x8 bfr = *(const bf16x8*)&se[h * 16 + l15][kk * 16 + quad * 4];
#pragma unroll
      for (int i = 0; i < 2; ++i) {
        bf16x8 afr = *(const bf16x8*)(wqf + (size_t)(((w * 2 + i) * 4 + kk) * 64 + lane) * 8);
        qacc[i] = __builtin_amdgcn_mfma_f32_16x16x32_bf16(afr, bfr, qacc[i], 0, 0, 0);
      }
    }
    int px = h * 16 + l15;
    float sv = simL[px];
    int n = y * 64 + xh + px;
#pragma unroll
    for (int i = 0; i < 2; ++i) {
      int o = (w * 2 + i) * 16 + quad * 4;
      float4 bq = *(const float4*)(b_q + o);
      us4 pk = { f2bf(sv * qacc[i][0] + bq.x), f2bf(sv * qacc[i][1] + bq.y),
                 f2bf(sv * qacc[i][2] + bq.z), f2bf(sv * qacc[i][3] + bq.w) };
      *(us4*)(qtb + ((size_t)b * N + n) * 256 + o) = pk;
    }
  }

  __syncthreads();
  // coalesced v2b stores (padded ch-major); 512 threads cover 128 ch x 4 segs
  {
    int ch = t >> 2, seg = t & 3;
    *(bf16x8*)(v2b + ((size_t)b * 128 + ch) * PIMG + np0 + seg * 8) =
        *(const bf16x8*)&vstg[ch * 40 + seg * 8];
  }
}

// ======== attention: R7 config (512 blocks, 8 waves, 18-wide window) ===========
__global__ __launch_bounds__(512, 2) void attn_kernel(const ushort_t* __restrict__ qtb,
                                                      const ushort_t* __restrict__ ktb,
                                                      const ushort_t* __restrict__ v2b,
                                                      const float* __restrict__ b_fusion,
                                                      float* __restrict__ out) {
  // XCD swizzle: same (L & 7) -> same XCD; each XCD owns one (batch, y-half-band).
  int L = blockIdx.x;                          // 512 blocks
  int xcd = L & 7, j = L >> 3;                 // j in [0,64)
  int b = xcd >> 1;
  int ty0 = (((xcd & 1) << 3) + (j >> 3)) * 4; // 16 y-tiles of 4 rows
  int tx0 = (j & 7) * 8;                       // 8 x-tiles of 8 cols
  int y0 = max(ty0 - 5, 0), y1 = min(ty0 + 8, 63);
  int nh = y1 - y0 + 1;                        // 9..14
  int xq0 = tx0 - 5, cb = tx0;                 // 18-wide QK window [tx0-5, tx0+12]
  int ntq = (nh * 18 + 15) >> 4;               // 16-key tiles over 18-wide enum, <= 16
  int npv = (nh * 3 + 3) >> 2;                 // 32-key PV chunks (24-wide enum), <= 11

  __shared__ ushort_t pst[32][352];            // P bf16 [q 32][key24], 704B rows
  __shared__ float reds[8][2][16];

  int t = threadIdx.x, w = t >> 6, lane = t & 63;   // w 0..7
  int l15 = lane & 15, quad = lane >> 4;

  // full zero of pst: 32 rows x 176 u32; 512 threads x 11 u32, no divides
  {
    uint_t* pr = (uint_t*)&pst[t & 31][0] + (t >> 5) * 11;
#pragma unroll
    for (int cc = 0; cc < 11; ++cc) pr[cc] = 0;
  }

  // Q B-frags for both 8x2 subtiles, direct from qtb (held in regs)
  int n_s0 = (ty0 + (l15 >> 3)) * 64 + tx0 + (l15 & 7);
  int n_s1 = n_s0 + 128;                       // +2 rows
  bf16x8 qfr[2][8];
  {
    const ushort_t* q0 = qtb + ((size_t)b * N + n_s0) * 256 + quad * 8;
    const ushort_t* q1 = qtb + ((size_t)b * N + n_s1) * 256 + quad * 8;
#pragma unroll
    for (int ks = 0; ks < 8; ++ks) {
      qfr[0][ks] = *(const bf16x8*)(q0 + ks * 32);
      qfr[1][ks] = *(const bf16x8*)(q1 + ks * 32);
    }
  }
  int qx = tx0 + (l15 & 7);
  int qy0 = ty0 + (l15 >> 3);                  // subtile 0; subtile 1 = +2

  // ---- phase 1: QK^T over 18-wide enum; wave w: key-tiles w, w+8 ----
  const ushort_t* kb = ktb + (size_t)b * PIMG * 256;
  f32x4 sc[2][2];
#pragma unroll
  for (int i = 0; i < 2; ++i) {
    int tq = w + i * 8;
    if (tq >= ntq) break;
    int key = tq * 16 + l15;
    int ry = (key * 3641) >> 16;               // key / 18 (exact for key < 256)
    int rx = key - ry * 18;
    int yy = min(y0 + ry, 63);
    const ushort_t* krow = kb + (size_t)(yy * PW + cb + 3 + rx) * 256 + quad * 8;
    f32x4 a0 = (f32x4){0.f,0.f,0.f,0.f}, a1 = (f32x4){0.f,0.f,0.f,0.f};
#pragma unroll
    for (int ks = 0; ks < 8; ++ks) {
      bf16x8 afr = *(const bf16x8*)(krow + ks * 32);
      a0 = __builtin_amdgcn_mfma_f32_16x16x32_bf16(afr, qfr[0][ks], a0, 0, 0, 0);
      a1 = __builtin_amdgcn_mfma_f32_16x16x32_bf16(afr, qfr[1][ks], a1, 0, 0, 0);
    }
    sc[i][0] = a0; sc[i][1] = a1;
  }

  // ---- phase 2 (fused): mask + exp (fixed shift) + row-sum + P scatter ----
  float mysum0 = 0.f, mysum1 = 0.f;
#pragma unroll
  for (int i = 0; i < 2; ++i) {
    int tq = w + i * 8;
    if (tq >= ntq) break;
#pragma unroll
    for (int r = 0; r < 4; ++r) {
      int key = tq * 16 + quad * 4 + r;
      int ry = (key * 3641) >> 16;
      int rx = key - ry * 18;
      int x = xq0 + rx;
      int dx = x - qx;
      bool xok = (dx >= -5) && (dx <= 5) && (x >= 0) && (x <= 63) && (ry < nh);
      int dy0 = y0 + ry - qy0;
      float e0 = (xok && dy0 >= -5 && dy0 <= 5) ? expf(sc[i][0][r] * 0.0625f) : 0.f;
      int dy1 = dy0 - 2;
      float e1 = (xok && dy1 >= -5 && dy1 <= 5) ? expf(sc[i][1][r] * 0.0625f) : 0.f;
      mysum0 += e0; mysum1 += e1;
      int k24 = ry * 24 + rx + 3;              // max 342 < 352, in-bounds
      pst[l15][k24]      = f2bf(e0);
      pst[16 + l15][k24] = f2bf(e1);
    }
  }
  mysum0 += __shfl_xor(mysum0, 16, 64); mysum0 += __shfl_xor(mysum0, 32, 64);
  mysum1 += __shfl_xor(mysum1, 16, 64); mysum1 += __shfl_xor(mysum1, 32, 64);
  if (quad == 0) { reds[w][0][l15] = mysum0; reds[w][1][l15] = mysum1; }
  __syncthreads();

  float rinv0 = 1.f / (reds[0][0][l15] + reds[1][0][l15] + reds[2][0][l15] + reds[3][0][l15] +
                       reds[4][0][l15] + reds[5][0][l15] + reds[6][0][l15] + reds[7][0][l15]);
  float rinv1 = 1.f / (reds[0][1][l15] + reds[1][1][l15] + reds[2][1][l15] + reds[3][1][l15] +
                       reds[4][1][l15] + reds[5][1][l15] + reds[6][1][l15] + reds[7][1][l15]);

  // ---- phase 3: PV. A = V (direct global b128); wave w owns 16 channels ----
  const ushort_t* vb = v2b + (size_t)b * 128 * PIMG;
  {
    int ch0 = w * 16;
    const ushort_t* vrow = vb + (size_t)(ch0 + l15) * PIMG;
    f32x4 acc0 = (f32x4){0.f,0.f,0.f,0.f}, acc1 = (f32x4){0.f,0.f,0.f,0.f};
    for (int ks = 0; ks < npv; ++ks) {
      int kst = ks * 32 + quad * 8;            // never crosses a 24-key row
      int ry = (kst * 2731) >> 16;             // kst / 24
      int rxs = kst - ry * 24;
      int yy = min(y0 + ry, 63);
      bf16x8 av = *(const bf16x8*)(vrow + yy * PW + cb + rxs);
      bf16x8 bp0 = *(const bf16x8*)(&pst[l15][kst]);
      bf16x8 bp1 = *(const bf16x8*)(&pst[16 + l15][kst]);
      acc0 = __builtin_amdgcn_mfma_f32_16x16x32_bf16(av, bp0, acc0, 0, 0, 0);
      acc1 = __builtin_amdgcn_mfma_f32_16x16x32_bf16(av, bp1, acc1, 0, 0, 0);
    }
    int chg = ch0 + quad * 4;
    float4 bf4 = *(const float4*)(b_fusion + chg);
    float bfa[4] = {bf4.x, bf4.y, bf4.z, bf4.w};
#pragma unroll
    for (int r = 0; r < 4; ++r) {
      out[((size_t)b * 128 + chg + r) * N + n_s0] = acc0[r] * rinv0 + bfa[r];
      out[((size_t)b * 128 + chg + r) * N + n_s1] = acc1[r] * rinv1 + bfa[r];
    }
  }
}

extern "C" void kernel_launch(void* const* d_in, const int* in_sizes, int n_in,
                              void* d_out, int out_size, void* d_ws, size_t ws_size,
                              hipStream_t stream) {
  (void)in_sizes; (void)n_in; (void)out_size; (void)ws_size;
  const float* edge_f  = (const float*)d_in[0];
  const float* sem     = (const float*)d_in[1];
  const float* fused_f = (const float*)d_in[2];
  const float* w_align = (const float*)d_in[3];
  const float* b_align = (const float*)d_in[4];
  const float* w_fal   = (const float*)d_in[5];
  const float* b_fal   = (const float*)d_in[6];
  const float* w_q     = (const float*)d_in[7];
  const float* b_q     = (const float*)d_in[8];
  const float* w_k     = (const float*)d_in[9];
  const float* b_k     = (const float*)d_in[10];
  const float* w_fus   = (const float*)d_in[11];
  const float* b_fus   = (const float*)d_in[12];
  float* out = (float*)d_out;

  float* ws = (float*)d_ws;
  float* edge32   = ws;                              // 524288
  float* fused32  = ws + 524288;                     // 524288
  float* dsum     = ws + 1081344;                    // 4 (+pad)
  ushort_t* wqf      = (ushort_t*)(ws + 3194880);    // 32768 us (frag-order)
  ushort_t* wkf      = (ushort_t*)(ws + 3211264);    // 65536 us
  ushort_t* wff      = (ushort_t*)(ws + 3244032);    // 32768 us
  ushort_t* qtb      = (ushort_t*)(ws + 3260416);    // 4194304 us [b][n][256]
  ushort_t* ktb      = (ushort_t*)(ws + 5357568);    // 5242880 us [b][5120][256] padded
  ushort_t* v2b      = (ushort_t*)(ws + 7979008);    // 2621440 us [b][128][5120] padded
  // (xt_sem/xt_fused/l2e slots retired; other offsets stable)

  prep_misc<<<576, 256, 0, stream>>>(edge_f, w_align, b_align, fused_f, w_fal, b_fal,
                                     w_q, w_k, w_fus, wqf, wkf, wff, edge32, fused32, dsum);
  l2ek<<<dim3(128, NB), 512, 0, stream>>>(edge32, dsum);
  prep_acts<<<dim3(128, NB), 512, 0, stream>>>(edge32, fused32, sem, wqf, wkf, wff,
                                               b_q, b_k, dsum, qtb, ktb, v2b);
  attn_kernel<<<512, 512, 0, stream>>>(qtb, ktb, v2b, b_fus, out);
}